// Round 1
// baseline (110.758 us; speedup 1.0000x reference)
//
#include <hip/hip_runtime.h>
#include <math.h>

#define BB 16
#define PP 16384
#define TT 64
#define CC 85
#define NUMCLS 80

// ws layout (floats):
// [0..1023]     box loss per (b,t)
// [1024..2047]  cls loss per (b,t)
// [2048..3071]  conf softplus partial per block
// [3072..3087]  conf matched partial per batch
// [4096..5119]  matched indices (as int)

__global__ __launch_bounds__(256) void match_kernel(const float* __restrict__ raw,
                                                    const float* __restrict__ tgt,
                                                    float* __restrict__ box_out,
                                                    float* __restrict__ cls_out,
                                                    int* __restrict__ matched) {
#pragma clang fp contract(off)
    int bt = blockIdx.x;              // 0..B*T-1
    int b = bt / TT, t = bt % TT;
    const float* trow = tgt + (size_t)(b * TT + t) * 5;
    float tx1 = trow[0], ty1 = trow[1], tx2 = trow[2], ty2 = trow[3];
    int tcls = (int)trow[4];
    float area_t = (tx2 - tx1) * (ty2 - ty1);

    const float* base = raw + (size_t)b * PP * CC;
    float best = -1.0f;
    int bidx = 0x7fffffff;
    for (int p = threadIdx.x; p < PP; p += 256) {
        const float* pr = base + (size_t)p * CC;
        float px1 = pr[0], py1 = pr[1], px2 = pr[2], py2 = pr[3];
        float x1 = fmaxf(px1, tx1), y1 = fmaxf(py1, ty1);
        float x2 = fminf(px2, tx2), y2 = fminf(py2, ty2);
        float w = x2 - x1, h = y2 - y1;
        float inter = w * h;
        bool valid = (w > 0.0f) && (h > 0.0f);
        float area_p = (px2 - px1) * (py2 - py1);
        float uni = (area_p + area_t) - inter;
        float iou = (valid && (uni > 0.0f)) ? (inter / uni) : 0.0f;
        if (iou > best || (iou == best && p < bidx)) { best = iou; bidx = p; }
    }

    __shared__ float sv[256];
    __shared__ int   si[256];
    sv[threadIdx.x] = best;
    si[threadIdx.x] = bidx;
    __syncthreads();
    for (int s = 128; s > 0; s >>= 1) {
        if (threadIdx.x < s) {
            float v2 = sv[threadIdx.x + s];
            int   i2 = si[threadIdx.x + s];
            if (v2 > sv[threadIdx.x] || (v2 == sv[threadIdx.x] && i2 < si[threadIdx.x])) {
                sv[threadIdx.x] = v2;
                si[threadIdx.x] = i2;
            }
        }
        __syncthreads();
    }
    int m = si[0];
    if (threadIdx.x == 0) matched[bt] = m;

    const float* prow = base + (size_t)m * CC;

    // box loss (thread 0, 4 coords)
    if (threadIdx.x == 0) {
        float s = 0.0f;
        float tb4[4] = {tx1, ty1, tx2, ty2};
        for (int i = 0; i < 4; ++i) {
            float d = fabsf(prow[i] - tb4[i]);
            s += (d < 1.0f) ? 0.5f * d * d : (d - 0.5f);
        }
        box_out[bt] = s;
    }

    // cls loss: log-softmax over 80 logits
    __shared__ float red[256];
    float x = (threadIdx.x < NUMCLS) ? prow[5 + threadIdx.x] : -INFINITY;
    red[threadIdx.x] = x;
    __syncthreads();
    for (int s = 128; s > 0; s >>= 1) {
        if (threadIdx.x < s) red[threadIdx.x] = fmaxf(red[threadIdx.x], red[threadIdx.x + s]);
        __syncthreads();
    }
    float mx = red[0];
    __syncthreads();
    red[threadIdx.x] = (threadIdx.x < NUMCLS) ? expf(x - mx) : 0.0f;
    __syncthreads();
    for (int s = 128; s > 0; s >>= 1) {
        if (threadIdx.x < s) red[threadIdx.x] += red[threadIdx.x + s];
        __syncthreads();
    }
    if (threadIdx.x == 0) {
        float lse = mx + logf(red[0]);
        cls_out[bt] = lse - prow[5 + tcls];
    }
}

__global__ __launch_bounds__(256) void conf_kernel(const float* __restrict__ raw,
                                                   float* __restrict__ partials) {
    int tid = blockIdx.x * 256 + threadIdx.x;   // exactly B*P threads
    float x = raw[(size_t)tid * CC + 4];
    float s = fmaxf(x, 0.0f) + log1pf(expf(-fabsf(x)));

    __shared__ float red[256];
    red[threadIdx.x] = s;
    __syncthreads();
    for (int st = 128; st > 0; st >>= 1) {
        if (threadIdx.x < st) red[threadIdx.x] += red[threadIdx.x + st];
        __syncthreads();
    }
    if (threadIdx.x == 0) partials[blockIdx.x] = red[0];
}

__global__ __launch_bounds__(64) void conf_matched_kernel(const float* __restrict__ raw,
                                                          const int* __restrict__ matched,
                                                          float* __restrict__ partials) {
    int b = blockIdx.x;
    int t = threadIdx.x;   // 64 threads
    int m = matched[b * TT + t];
    bool first = true;
    for (int t2 = 0; t2 < t; ++t2) {
        if (matched[b * TT + t2] == m) { first = false; break; }
    }
    float v = first ? raw[((size_t)b * PP + m) * CC + 4] : 0.0f;
    for (int off = 32; off > 0; off >>= 1) v += __shfl_down(v, off);
    if (t == 0) partials[b] = v;
}

__global__ __launch_bounds__(256) void finalize_kernel(const float* __restrict__ ws,
                                                       float* __restrict__ out) {
    float box = 0.0f, cls = 0.0f, conf = 0.0f;
    for (int i = threadIdx.x; i < 1024; i += 256) {
        box  += ws[i];
        cls  += ws[1024 + i];
        conf += ws[2048 + i];
    }
    if (threadIdx.x < 16) conf -= ws[3072 + threadIdx.x];   // subtract matched conf logits
    float tot = 5.0f * box + 1.0f * cls + conf;

    __shared__ float red[256];
    red[threadIdx.x] = tot;
    __syncthreads();
    for (int s = 128; s > 0; s >>= 1) {
        if (threadIdx.x < s) red[threadIdx.x] += red[threadIdx.x + s];
        __syncthreads();
    }
    if (threadIdx.x == 0) out[0] = red[0] / (float)BB;
}

extern "C" void kernel_launch(void* const* d_in, const int* in_sizes, int n_in,
                              void* d_out, int out_size, void* d_ws, size_t ws_size,
                              hipStream_t stream) {
    const float* raw = (const float*)d_in[0];
    const float* tgt = (const float*)d_in[1];
    float* out = (float*)d_out;
    float* wsf = (float*)d_ws;

    float* box_p  = wsf;
    float* cls_p  = wsf + 1024;
    float* confA  = wsf + 2048;
    float* confB  = wsf + 3072;
    int*   match  = (int*)(wsf + 4096);

    match_kernel<<<BB * TT, 256, 0, stream>>>(raw, tgt, box_p, cls_p, match);
    conf_kernel<<<(BB * PP) / 256, 256, 0, stream>>>(raw, confA);
    conf_matched_kernel<<<BB, TT, 0, stream>>>(raw, match, confB);
    finalize_kernel<<<1, 256, 0, stream>>>(wsf, out);
}

// Round 2
// 43.144 us; speedup vs baseline: 2.5672x; 2.5672x over previous
//
#include <hip/hip_runtime.h>
#include <math.h>

#define BB 16
#define PP 16384
#define TT 64
#define CC 85
#define NUMCLS 80
#define CHUNK 512
#define NCHUNK (PP / CHUNK)   // 32

// ws layout (floats):
// [0..1023]        box loss per (b,t)
// [1024..2047]     cls loss per (b,t)
// [2048..2559]     conf softplus partial per pass1 block (512)
// [3072..3087]     conf matched partial per batch (16)
// [4096..5119]     matched indices (int) per (b,t)
// [8192..40959]    cand_val  [b][t][chunk]  (16*64*32 = 32768)
// [49152..81919]   cand_idx  (int)          (32768)

__global__ __launch_bounds__(256) void pass1_kernel(const float* __restrict__ raw,
                                                    const float* __restrict__ tgt,
                                                    float* __restrict__ cand_val,
                                                    int* __restrict__ cand_idx,
                                                    float* __restrict__ conf_part) {
#pragma clang fp contract(off)
    int b = blockIdx.x / NCHUNK;
    int chunk = blockIdx.x % NCHUNK;
    int p0 = chunk * CHUNK;
    const float* base = raw + (size_t)b * PP * CC;

    __shared__ float4 sbox[CHUNK];       // 8 KB
    __shared__ float  sval[4][64];
    __shared__ int    sidx[4][64];
    __shared__ float  red[256];

    // Stage boxes + accumulate softplus(conf) in one pass over row heads.
    float conf_acc = 0.0f;
    for (int i = threadIdx.x; i < CHUNK; i += 256) {
        const float* pr = base + (size_t)(p0 + i) * CC;
        float x1 = pr[0], y1 = pr[1], x2 = pr[2], y2 = pr[3], c = pr[4];
        sbox[i] = make_float4(x1, y1, x2, y2);
        conf_acc += fmaxf(c, 0.0f) + log1pf(expf(-fabsf(c)));
    }
    __syncthreads();

    int wave = threadIdx.x >> 6;
    int lane = threadIdx.x & 63;

    // Lane l owns target l. Wave w scans preds [p0 + w*128, p0 + (w+1)*128).
    const float* trow = tgt + (size_t)(b * TT + lane) * 5;
    float tx1 = trow[0], ty1 = trow[1], tx2 = trow[2], ty2 = trow[3];
    float area_t = (tx2 - tx1) * (ty2 - ty1);

    float best = -1.0f;
    int bidx = 0x7fffffff;
    int j0 = wave * (CHUNK / 4);
    for (int j = 0; j < CHUNK / 4; ++j) {
        float4 pb = sbox[j0 + j];            // uniform addr per wave -> broadcast
        float x1 = fmaxf(pb.x, tx1), y1 = fmaxf(pb.y, ty1);
        float x2 = fminf(pb.z, tx2), y2 = fminf(pb.w, ty2);
        float w = x2 - x1, h = y2 - y1;
        float inter = w * h;
        bool valid = (w > 0.0f) && (h > 0.0f);
        float area_p = (pb.z - pb.x) * (pb.w - pb.y);
        float uni = (area_p + area_t) - inter;
        float iou = (valid && (uni > 0.0f)) ? (inter / uni) : 0.0f;
        if (iou > best) { best = iou; bidx = p0 + j0 + j; }   // ascending idx -> '>' keeps first max
    }

    sval[wave][lane] = best;
    sidx[wave][lane] = bidx;

    // softplus block-reduce
    red[threadIdx.x] = conf_acc;
    __syncthreads();
    for (int s = 128; s > 0; s >>= 1) {
        if (threadIdx.x < s) red[threadIdx.x] += red[threadIdx.x + s];
        __syncthreads();
    }
    if (threadIdx.x == 0) conf_part[blockIdx.x] = red[0];

    // cross-wave (4-way) candidate reduce, wave 0
    if (wave == 0) {
        float v = sval[0][lane];
        int   i = sidx[0][lane];
        for (int w2 = 1; w2 < 4; ++w2) {
            float v2 = sval[w2][lane];
            int   i2 = sidx[w2][lane];
            if (v2 > v || (v2 == v && i2 < i)) { v = v2; i = i2; }
        }
        size_t o = (size_t)(b * TT + lane) * NCHUNK + chunk;
        cand_val[o] = v;
        cand_idx[o] = i;
    }
}

__global__ __launch_bounds__(64) void pass2_kernel(const float* __restrict__ raw,
                                                   const float* __restrict__ tgt,
                                                   const float* __restrict__ cand_val,
                                                   const int* __restrict__ cand_idx,
                                                   float* __restrict__ box_out,
                                                   float* __restrict__ cls_out,
                                                   int* __restrict__ matched) {
#pragma clang fp contract(off)
    int bt = blockIdx.x;          // 0..1023
    int b = bt / TT;
    int lane = threadIdx.x;       // 64

    float v = -2.0f;
    int   i = 0x7fffffff;
    if (lane < NCHUNK) {
        size_t o = (size_t)bt * NCHUNK + lane;
        v = cand_val[o];
        i = cand_idx[o];
    }
    for (int m = 1; m < 64; m <<= 1) {
        float ov = __shfl_xor(v, m);
        int   oi = __shfl_xor(i, m);
        if (ov > v || (ov == v && oi < i)) { v = ov; i = oi; }
    }
    int m = i;   // all lanes agree
    if (lane == 0) matched[bt] = m;

    const float* prow = raw + ((size_t)b * PP + m) * CC;
    const float* trow = tgt + (size_t)bt * 5;

    // log-softmax over 80 logits: lane covers class lane; lane<16 also class lane+64
    float l0 = prow[5 + lane];
    float l1 = (lane < 16) ? prow[5 + 64 + lane] : -INFINITY;
    float mx = fmaxf(l0, l1);
    for (int s = 1; s < 64; s <<= 1) mx = fmaxf(mx, __shfl_xor(mx, s));
    float e = expf(l0 - mx) + ((lane < 16) ? expf(l1 - mx) : 0.0f);
    for (int s = 1; s < 64; s <<= 1) e += __shfl_xor(e, s);

    if (lane == 0) {
        int tcls = (int)trow[4];
        cls_out[bt] = (mx + logf(e)) - prow[5 + tcls];

        float s = 0.0f;
        for (int k = 0; k < 4; ++k) {
            float d = fabsf(prow[k] - trow[k]);
            s += (d < 1.0f) ? 0.5f * d * d : (d - 0.5f);
        }
        box_out[bt] = s;
    }
}

__global__ __launch_bounds__(64) void conf_matched_kernel(const float* __restrict__ raw,
                                                          const int* __restrict__ matched,
                                                          float* __restrict__ partials) {
    int b = blockIdx.x;
    int t = threadIdx.x;   // 64
    int m = matched[b * TT + t];
    bool first = true;
    for (int t2 = 0; t2 < t; ++t2) {
        if (matched[b * TT + t2] == m) { first = false; break; }
    }
    float v = first ? raw[((size_t)b * PP + m) * CC + 4] : 0.0f;
    for (int off = 32; off > 0; off >>= 1) v += __shfl_down(v, off);
    if (t == 0) partials[b] = v;
}

__global__ __launch_bounds__(256) void finalize_kernel(const float* __restrict__ ws,
                                                       float* __restrict__ out) {
    float box = 0.0f, cls = 0.0f, conf = 0.0f;
    for (int i = threadIdx.x; i < 1024; i += 256) {
        box += ws[i];
        cls += ws[1024 + i];
    }
    for (int i = threadIdx.x; i < 512; i += 256) conf += ws[2048 + i];
    if (threadIdx.x < 16) conf -= ws[3072 + threadIdx.x];
    float tot = 5.0f * box + 1.0f * cls + conf;

    __shared__ float red[256];
    red[threadIdx.x] = tot;
    __syncthreads();
    for (int s = 128; s > 0; s >>= 1) {
        if (threadIdx.x < s) red[threadIdx.x] += red[threadIdx.x + s];
        __syncthreads();
    }
    if (threadIdx.x == 0) out[0] = red[0] / (float)BB;
}

extern "C" void kernel_launch(void* const* d_in, const int* in_sizes, int n_in,
                              void* d_out, int out_size, void* d_ws, size_t ws_size,
                              hipStream_t stream) {
    const float* raw = (const float*)d_in[0];
    const float* tgt = (const float*)d_in[1];
    float* out = (float*)d_out;
    float* wsf = (float*)d_ws;

    float* box_p   = wsf;
    float* cls_p   = wsf + 1024;
    float* confA   = wsf + 2048;
    float* confB   = wsf + 3072;
    int*   match   = (int*)(wsf + 4096);
    float* cand_v  = wsf + 8192;
    int*   cand_i  = (int*)(wsf + 49152);

    pass1_kernel<<<BB * NCHUNK, 256, 0, stream>>>(raw, tgt, cand_v, cand_i, confA);
    pass2_kernel<<<BB * TT, 64, 0, stream>>>(raw, tgt, cand_v, cand_i, box_p, cls_p, match);
    conf_matched_kernel<<<BB, TT, 0, stream>>>(raw, match, confB);
    finalize_kernel<<<1, 256, 0, stream>>>(wsf, out);
}